// Round 6
// baseline (361.303 us; speedup 1.0000x reference)
//
#include <hip/hip_runtime.h>
#include <cstdint>

#define N_VIS   8192
#define N_ASSOC 4096
#define N_MOTOR 1024
#define IN_DIM  4096
#define T_STEPS 16

// ---------------- encoder + visual LIF: x staged in LDS, 2 rows/wave, 8 rows/block ----------------
__global__ __launch_bounds__(256, 4) void encoder_kernel(
        const float* __restrict__ x, const float* __restrict__ noise,
        const float* __restrict__ W, const float* __restrict__ b,
        unsigned* __restrict__ vmask) {
    __shared__ float4 xs[16 * 64];               // [t][64 float4] tile of one 256-col chunk (16 KB)
    const int tid = threadIdx.x;
    const int wave = tid >> 6, lane = tid & 63;
    const int r0 = blockIdx.x * 8 + wave * 2;    // this wave's two rows
    const float4* W0 = (const float4*)(W + (size_t)r0 * IN_DIM);
    const float4* W1 = (const float4*)(W + (size_t)(r0 + 1) * IN_DIM);

    float a0[T_STEPS], a1[T_STEPS];
#pragma unroll
    for (int t = 0; t < T_STEPS; ++t) { a0[t] = 0.f; a1[t] = 0.f; }

    for (int c = 0; c < 16; ++c) {
        __syncthreads();
#pragma unroll
        for (int p = 0; p < 4; ++p) {
            int f = tid + p * 256;               // flat index over [16 t][64 c4]
            int t = f >> 6, c4 = f & 63;
            xs[f] = ((const float4*)(x + (size_t)t * IN_DIM + c * 256))[c4];
        }
        __syncthreads();
        float4 w0 = W0[c * 64 + lane];
        float4 w1 = W1[c * 64 + lane];
#pragma unroll
        for (int t = 0; t < T_STEPS; ++t) {
            float4 xv = xs[t * 64 + lane];
            a0[t] += w0.x*xv.x + w0.y*xv.y + w0.z*xv.z + w0.w*xv.w;
            a1[t] += w1.x*xv.x + w1.y*xv.y + w1.z*xv.z + w1.w*xv.w;
        }
    }
#pragma unroll
    for (int t = 0; t < T_STEPS; ++t) {
        float v;
        v = a0[t]; for (int o = 32; o; o >>= 1) v += __shfl_xor(v, o, 64); a0[t] = v;
        v = a1[t]; for (int o = 32; o; o >>= 1) v += __shfl_xor(v, o, 64); a1[t] = v;
    }
    if (lane == 0) {
        auto do_row = [&](int i, const float (&a)[T_STEPS]) {
            float bb = b[i];
            float v = 0.f;
            unsigned msk = 0;
#pragma unroll
            for (int t = 0; t < T_STEPS; ++t) {
                float logit = a[t] + bb;
                float rate = 1.0f / (1.0f + expf(-logit));
                float u = noise[t * N_VIS + i];
                float ins = (u < rate * 0.3f) ? 1.0f : 0.0f;
                v = v * 0.95f + ins;
                if (v > 1.0f) { msk |= (1u << t); v = 0.f; }
            }
            vmask[i] = msk;
        };
        do_row(r0, a0);
        do_row(r0 + 1, a1);
    }
}

// ---------------- snn layer: ONE row per 1024-thread block; tiny per-thread state ----------------
// NC = float4 chunks per thread (row length = NC * 4096 floats). VA: NC=2, AM: NC=1.
// Per-thread live state ~45 VGPRs -> guaranteed arch-VGPR allocation, no AGPR shuttle.
template<int NC>
__global__ __launch_bounds__(1024, 4) void snn_layer_kernel(
        const float* __restrict__ Wg, const unsigned* __restrict__ colmask,
        const float* __restrict__ dop, unsigned* __restrict__ rowmask_out,
        float* __restrict__ outp, int out_stride) {
    const int j = blockIdx.x;
    const int tid = threadIdx.x;
    const int lane = tid & 63, wv = tid >> 6;        // 16 waves
    __shared__ float sred[2][16];                    // [pingpong][wave]
    __shared__ float sdop[T_STEPS];
    if (tid < T_STEPS) sdop[tid] = dop[tid];

    const float4* Wr = (const float4*)(Wg + (size_t)j * (NC * 4096));
    const uint4*  cm = (const uint4*)colmask;

    float w[NC*4], e[NC*4], bf[NC*4];
    unsigned vmp[NC*2];                              // packed: low16 = {x,z}, high16 = {y,w}
#pragma unroll
    for (int k = 0; k < NC; ++k) {
        float4 q  = Wr[tid + k*1024];
        uint4  mv = cm[tid + k*1024];
        w[k*4+0]=q.x; w[k*4+1]=q.y; w[k*4+2]=q.z; w[k*4+3]=q.w;
        vmp[k*2+0] = mv.x | (mv.y << 16);
        vmp[k*2+1] = mv.z | (mv.w << 16);
        e[k*4+0]=0.f; e[k*4+1]=0.f; e[k*4+2]=0.f; e[k*4+3]=0.f;
    }
    __syncthreads();                                 // covers sdop too

    float decay_next = 0.998f;
    float vmem = 0.f;
    unsigned rm = 0;
    bool st = false;                                 // row has spiked at least once

#pragma unroll 1
    for (int t = 0; t < T_STEPS; ++t) {
        // ---- matvec against column-spikes of step t; keep bit->float in bf[] ----
        float acc = 0.f;
#pragma unroll
        for (int k = 0; k < NC; ++k) {
            float bx = (float)((vmp[k*2+0] >> t)        & 1u);
            float by = (float)((vmp[k*2+0] >> (t + 16)) & 1u);
            float bz = (float)((vmp[k*2+1] >> t)        & 1u);
            float bw = (float)((vmp[k*2+1] >> (t + 16)) & 1u);
            bf[k*4+0]=bx; bf[k*4+1]=by; bf[k*4+2]=bz; bf[k*4+3]=bw;
            acc = fmaf(w[k*4+0], bx, acc); acc = fmaf(w[k*4+1], by, acc);
            acc = fmaf(w[k*4+2], bz, acc); acc = fmaf(w[k*4+3], bw, acc);
        }
        for (int o = 32; o; o >>= 1) acc += __shfl_down(acc, o, 64);
        if (lane == 0) sred[t & 1][wv] = acc;
        __syncthreads();

        // ---- LIF, redundantly on all threads (identical FP ops -> identical results) ----
        const float* sp = sred[t & 1];
        float tot = sp[0];
#pragma unroll
        for (int q = 1; q < 16; ++q) tot += sp[q];
        vmem = vmem * 0.95f + tot * 0.1f;
        const bool s = vmem > 1.0f;
        if (s) { vmem = 0.f; rm |= (1u << t); }
        if (outp && tid == 0) outp[t * out_stride + j] = s ? 1.0f : 0.0f;

        // ---- eligibility + gated plastic update (dead at t=15; dead until first spike) ----
        if (t != T_STEPS - 1) {
            const float d  = sdop[t];
            const bool  g  = fabsf(d) > 0.1f;
            const float dm = decay_next;
            st |= s;
            const float inc = s ? 0.01f : 0.0f;
            if (st) {
                if (g) {
#pragma unroll
                    for (int el = 0; el < NC*4; ++el) {
                        e[el] = fmaf(e[el], dm, bf[el] * inc);
                        float dl = (d * e[el]) * 0.1f;                // ref op order
                        dl = fminf(fmaxf(dl, -0.01f), 0.01f);         // -> v_med3
                        w[el] = fmaxf(w[el] + dl, 0.0f);              // upper clip dead (w<=0.2)
                    }
                } else {
#pragma unroll
                    for (int el = 0; el < NC*4; ++el)
                        e[el] = fmaf(e[el], dm, bf[el] * inc);
                }
            }
            decay_next = g ? (0.998f * 0.5f) : 0.998f;                // bit-exact fold
        }
    }
    if (tid == 0 && rowmask_out) rowmask_out[j] = rm;
}

extern "C" void kernel_launch(void* const* d_in, const int* in_sizes, int n_in,
                              void* d_out, int out_size, void* d_ws, size_t ws_size,
                              hipStream_t stream) {
    const float* x     = (const float*)d_in[0];   // [16, 4096]
    const float* noise = (const float*)d_in[1];   // [16, 8192]
    const float* dop   = (const float*)d_in[2];   // [16]
    const float* W_enc = (const float*)d_in[3];   // [8192, 4096]
    const float* b_enc = (const float*)d_in[4];   // [8192]
    const float* W_va  = (const float*)d_in[5];   // [4096, 8192]
    const float* W_am  = (const float*)d_in[6];   // [1024, 4096]
    float* out = (float*)d_out;                   // [16, 1024] f32
    (void)in_sizes; (void)n_in; (void)out_size; (void)ws_size;

    unsigned* vmask = (unsigned*)d_ws;            // [8192]
    unsigned* amask = vmask + N_VIS;              // [4096]

    encoder_kernel<<<N_VIS / 8, 256, 0, stream>>>(x, noise, W_enc, b_enc, vmask);
    snn_layer_kernel<2><<<N_ASSOC, 1024, 0, stream>>>(W_va, vmask, dop, amask, nullptr, 0);
    snn_layer_kernel<1><<<N_MOTOR, 1024, 0, stream>>>(W_am, amask, dop, nullptr, out, N_MOTOR);
}

// Round 7
// 157.986 us; speedup vs baseline: 2.2869x; 2.2869x over previous
//
#include <hip/hip_runtime.h>
#include <cstdint>

#define N_VIS   8192
#define N_ASSOC 4096
#define N_MOTOR 1024
#define IN_DIM  4096
#define T_STEPS 16

// ---------------- encoder + visual LIF (unchanged from round 4; proven) ----------------
__global__ __launch_bounds__(256, 4) void encoder_kernel(
        const float* __restrict__ x, const float* __restrict__ noise,
        const float* __restrict__ W, const float* __restrict__ b,
        unsigned* __restrict__ vmask) {
    __shared__ float4 xs[16 * 64];
    const int tid = threadIdx.x;
    const int wave = tid >> 6, lane = tid & 63;
    const int r0 = blockIdx.x * 8 + wave * 2;
    const float4* W0 = (const float4*)(W + (size_t)r0 * IN_DIM);
    const float4* W1 = (const float4*)(W + (size_t)(r0 + 1) * IN_DIM);

    float a0[T_STEPS], a1[T_STEPS];
#pragma unroll
    for (int t = 0; t < T_STEPS; ++t) { a0[t] = 0.f; a1[t] = 0.f; }

    for (int c = 0; c < 16; ++c) {
        __syncthreads();
#pragma unroll
        for (int p = 0; p < 4; ++p) {
            int f = tid + p * 256;
            int t = f >> 6, c4 = f & 63;
            xs[f] = ((const float4*)(x + (size_t)t * IN_DIM + c * 256))[c4];
        }
        __syncthreads();
        float4 w0 = W0[c * 64 + lane];
        float4 w1 = W1[c * 64 + lane];
#pragma unroll
        for (int t = 0; t < T_STEPS; ++t) {
            float4 xv = xs[t * 64 + lane];
            a0[t] += w0.x*xv.x + w0.y*xv.y + w0.z*xv.z + w0.w*xv.w;
            a1[t] += w1.x*xv.x + w1.y*xv.y + w1.z*xv.z + w1.w*xv.w;
        }
    }
#pragma unroll
    for (int t = 0; t < T_STEPS; ++t) {
        float v;
        v = a0[t]; for (int o = 32; o; o >>= 1) v += __shfl_xor(v, o, 64); a0[t] = v;
        v = a1[t]; for (int o = 32; o; o >>= 1) v += __shfl_xor(v, o, 64); a1[t] = v;
    }
    if (lane == 0) {
        auto do_row = [&](int i, const float (&a)[T_STEPS]) {
            float bb = b[i];
            float v = 0.f;
            unsigned msk = 0;
#pragma unroll
            for (int t = 0; t < T_STEPS; ++t) {
                float logit = a[t] + bb;
                float rate = 1.0f / (1.0f + expf(-logit));
                float u = noise[t * N_VIS + i];
                float ins = (u < rate * 0.3f) ? 1.0f : 0.0f;
                v = v * 0.95f + ins;
                if (v > 1.0f) { msk |= (1u << t); v = 0.f; }
            }
            vmask[i] = msk;
        };
        do_row(r0, a0);
        do_row(r0 + 1, a1);
    }
}

// ---------------- K table: K[t][r] = sum_{s=r..t-1} g_s * d_s*0.1*0.01*C[s][r] ----------------
__global__ void ktab_kernel(const float* __restrict__ dop, float* __restrict__ K) {
    __shared__ float C[256];      // C[s*16+r]
    __shared__ float sd[16];
    __shared__ unsigned sg[16];
    const int p = threadIdx.x;    // 256 threads: p = s*16 + r  (then t*16 + r)
    if (p < 16) {
        float d = dop[p];
        sd[p] = d;
        sg[p] = (fabsf(d) > 0.1f) ? 1u : 0u;
    }
    __syncthreads();
    {
        const int s = p >> 4, r = p & 15;
        float c = 0.f;
        if (s >= r) {
            c = 1.f;                              // C[r][r] = 1
            for (int u = r; u < s; ++u) {         // same op order as sequential build
                if (sg[u]) c *= 0.5f;
                c *= 0.998f;
            }
        }
        C[p] = c;
    }
    __syncthreads();
    {
        const int t = p >> 4, r = p & 15;
        float kk = 0.f;
        for (int s = r; s < t; ++s)
            if (sg[s]) kk += ((sd[s] * 0.1f) * 0.01f) * C[s * 16 + r];
        K[p] = kk;
    }
}

// ---------------- OVL[r][t] = popcount over mask words of bit_r & bit_t ----------------
__global__ void ovl_kernel(const unsigned* __restrict__ mask, int words_per_block,
                           int* __restrict__ ovl) {
    const int p = threadIdx.x;            // 256 threads: p = r*16 + t
    const int r = p >> 4, t = p & 15;
    const unsigned* w = mask + blockIdx.x * words_per_block;
    int c = 0;
    for (int i = 0; i < words_per_block; ++i)
        c += (int)((w[i] >> r) & (w[i] >> t) & 1u);
    atomicAdd(&ovl[p], c);
}

// ---------------- base pass: base[j][t] = sum_i W0[j,i] * v_t(i), 2 rows per 256-thr block ----
// NC = float4 chunks per thread per row (row length = NC*1024 floats).
template<int NC>
__global__ __launch_bounds__(256) void base_kernel(
        const float* __restrict__ W0, const unsigned* __restrict__ colmask,
        float* __restrict__ base) {
    const int j0 = blockIdx.x * 2;
    const int tid = threadIdx.x;
    const int lane = tid & 63, wv = tid >> 6;      // 4 waves
    __shared__ float sred[4][32];

    const float4* Wr0 = (const float4*)(W0 + (size_t)j0 * (NC * 1024));
    const float4* Wr1 = (const float4*)(W0 + (size_t)(j0 + 1) * (NC * 1024));
    const uint4*  cm  = (const uint4*)colmask;

    float acc0[T_STEPS], acc1[T_STEPS];
#pragma unroll
    for (int t = 0; t < T_STEPS; ++t) { acc0[t] = 0.f; acc1[t] = 0.f; }

    for (int k = 0; k < NC; ++k) {
        float4 q0 = Wr0[tid + k * 256];
        float4 q1 = Wr1[tid + k * 256];
        uint4  m  = cm [tid + k * 256];
        unsigned plo = m.x | (m.y << 16);
        unsigned phi = m.z | (m.w << 16);
#pragma unroll
        for (int t = 0; t < T_STEPS; ++t) {
            float bx = (float)((plo >> t)        & 1u);
            float by = (float)((plo >> (t + 16)) & 1u);
            float bz = (float)((phi >> t)        & 1u);
            float bw = (float)((phi >> (t + 16)) & 1u);
            acc0[t] = fmaf(q0.x, bx, acc0[t]); acc0[t] = fmaf(q0.y, by, acc0[t]);
            acc0[t] = fmaf(q0.z, bz, acc0[t]); acc0[t] = fmaf(q0.w, bw, acc0[t]);
            acc1[t] = fmaf(q1.x, bx, acc1[t]); acc1[t] = fmaf(q1.y, by, acc1[t]);
            acc1[t] = fmaf(q1.z, bz, acc1[t]); acc1[t] = fmaf(q1.w, bw, acc1[t]);
        }
    }
#pragma unroll
    for (int t = 0; t < T_STEPS; ++t) {
        for (int o = 32; o; o >>= 1) acc0[t] += __shfl_down(acc0[t], o, 64);
        for (int o = 32; o; o >>= 1) acc1[t] += __shfl_down(acc1[t], o, 64);
    }
    if (lane == 0) {
#pragma unroll
        for (int t = 0; t < T_STEPS; ++t) {
            sred[wv][t]      = acc0[t];
            sred[wv][16 + t] = acc1[t];
        }
    }
    __syncthreads();
    if (tid < 32) {
        const int r = tid >> 4, t = tid & 15;
        float v = sred[0][tid] + sred[1][tid] + sred[2][tid] + sred[3][tid];
        base[(size_t)(j0 + r) * 16 + t] = v;
    }
}

// ---------------- tiny sequential recursion: one lane per row ----------------
__global__ __launch_bounds__(64) void rec_kernel(
        const float* __restrict__ base, const int* __restrict__ ovl,
        const float* __restrict__ K, unsigned* __restrict__ mask_out,
        float* __restrict__ outp, int out_stride) {
    __shared__ float KO[256];                     // KO[t*16+r] = K[t][r] * OVL[r][t]
    const int tid = threadIdx.x;
    for (int p = tid; p < 256; p += 64) {
        const int t = p >> 4, r = p & 15;
        KO[p] = K[p] * (float)ovl[r * 16 + t];
    }
    __syncthreads();

    const int j = blockIdx.x * 64 + tid;
    float br[T_STEPS];
#pragma unroll
    for (int t = 0; t < T_STEPS; ++t) br[t] = base[(size_t)j * 16 + t];

    float vmem = 0.f;
    unsigned am = 0;
#pragma unroll
    for (int t = 0; t < T_STEPS; ++t) {
        float I = br[t];
        for (int r = 0; r < t; ++r)
            if ((am >> r) & 1u) I += KO[t * 16 + r];
        vmem = vmem * 0.95f + I * 0.1f;
        const bool s = vmem > 1.0f;
        if (s) { vmem = 0.f; am |= (1u << t); }
        if (outp) outp[t * out_stride + j] = s ? 1.0f : 0.0f;
    }
    mask_out[j] = am;
}

extern "C" void kernel_launch(void* const* d_in, const int* in_sizes, int n_in,
                              void* d_out, int out_size, void* d_ws, size_t ws_size,
                              hipStream_t stream) {
    const float* x     = (const float*)d_in[0];   // [16, 4096]
    const float* noise = (const float*)d_in[1];   // [16, 8192]
    const float* dop   = (const float*)d_in[2];   // [16]
    const float* W_enc = (const float*)d_in[3];   // [8192, 4096]
    const float* b_enc = (const float*)d_in[4];   // [8192]
    const float* W_va  = (const float*)d_in[5];   // [4096, 8192]
    const float* W_am  = (const float*)d_in[6];   // [1024, 4096]
    float* out = (float*)d_out;                   // [16, 1024] f32
    (void)in_sizes; (void)n_in; (void)out_size; (void)ws_size;

    char* ws = (char*)d_ws;
    size_t off = 0;
    unsigned* vmask  = (unsigned*)(ws + off); off += N_VIS * 4;
    unsigned* amask  = (unsigned*)(ws + off); off += N_ASSOC * 4;
    unsigned* mmask  = (unsigned*)(ws + off); off += N_MOTOR * 4;
    float*    K      = (float*)(ws + off);    off += 256 * 4;
    int*      ovl_v  = (int*)(ws + off);      off += 256 * 4;
    int*      ovl_a  = (int*)(ws + off);      off += 256 * 4;
    float*    baseVA = (float*)(ws + off);    off += (size_t)N_ASSOC * 16 * 4;
    float*    baseAM = (float*)(ws + off);    off += (size_t)N_MOTOR * 16 * 4;

    hipMemsetAsync(ovl_v, 0, 2 * 256 * 4, stream);   // ovl_v and ovl_a are adjacent

    ktab_kernel<<<1, 256, 0, stream>>>(dop, K);
    encoder_kernel<<<N_VIS / 8, 256, 0, stream>>>(x, noise, W_enc, b_enc, vmask);
    ovl_kernel<<<32, 256, 0, stream>>>(vmask, N_VIS / 32, ovl_v);
    base_kernel<8><<<N_ASSOC / 2, 256, 0, stream>>>(W_va, vmask, baseVA);
    rec_kernel<<<N_ASSOC / 64, 64, 0, stream>>>(baseVA, ovl_v, K, amask, nullptr, 0);
    ovl_kernel<<<16, 256, 0, stream>>>(amask, N_ASSOC / 16, ovl_a);
    base_kernel<4><<<N_MOTOR / 2, 256, 0, stream>>>(W_am, amask, baseAM);
    rec_kernel<<<N_MOTOR / 64, 64, 0, stream>>>(baseAM, ovl_a, K, mmask, out, N_MOTOR);
}